// Round 1
// baseline (364.585 us; speedup 1.0000x reference)
//
#include <hip/hip_runtime.h>

#define TT 200
#define BB 4096
#define HH 32

__device__ __forceinline__ float fsigmoid(float x) {
    return __fdividef(1.0f, 1.0f + __expf(-x));
}
__device__ __forceinline__ float ftanh_fast(float x) {
    // tanh(x) = 1 - 2/(exp(2x)+1); saturates correctly for |x| large
    return 1.0f - __fdividef(2.0f, 1.0f + __expf(2.0f * x));
}

// Fill out[T*B] with fc_b[0]; grid sized exactly TT*BB/4 threads, float4 stores.
__global__ void gru_init_out(float* __restrict__ out, const float* __restrict__ fc_b) {
    int i = blockIdx.x * blockDim.x + threadIdx.x;
    float v = fc_b[0];
    ((float4*)out)[i] = make_float4(v, v, v, v);
}

// Persistent GRU scan. Thread (k, b-pair) owns hidden unit k for two batch rows,
// holds w_hh rows {k, 32+k, 64+k} in 96 VGPRs, h shared via LDS ping-pong.
// Block = 256 threads = 4 waves = 16 batch rows; grid = (B/16, 2 dirs).
__global__ __launch_bounds__(256, 2) void gru_scan_kernel(
    const float* __restrict__ x,
    const float* __restrict__ w_ih_f, const float* __restrict__ w_hh_f,
    const float* __restrict__ b_ih_f, const float* __restrict__ b_hh_f,
    const float* __restrict__ w_ih_b, const float* __restrict__ w_hh_b,
    const float* __restrict__ b_ih_b, const float* __restrict__ b_hh_b,
    const float* __restrict__ fc_w,
    float* __restrict__ out)
{
    const int dir   = blockIdx.y;
    const int lane  = threadIdx.x & 63;
    const int wv    = threadIdx.x >> 6;   // wave in block: 0..3
    const int k     = lane & 31;          // hidden unit
    const int half  = lane >> 5;          // half-wave: 0/1
    const int bloc0 = wv * 4 + half * 2;  // 0..14 (even)
    const int b0    = blockIdx.x * 16 + bloc0;

    const float* __restrict__ Wih = dir ? w_ih_b : w_ih_f;
    const float* __restrict__ Whh = dir ? w_hh_b : w_hh_f;
    const float* __restrict__ Bih = dir ? b_ih_b : b_ih_f;
    const float* __restrict__ Bhh = dir ? b_hh_b : b_hh_f;

    // ---- weight-stationary registers: rows k, 32+k, 64+k of w_hh [96x32] ----
    float wr[32], wz[32], wn[32];
    {
        const float4* W4 = (const float4*)Whh;   // rows are 128B aligned
        #pragma unroll
        for (int j = 0; j < 8; ++j) {
            float4 a = W4[(k)      * 8 + j];
            float4 c = W4[(32 + k) * 8 + j];
            float4 d = W4[(64 + k) * 8 + j];
            wr[4*j+0] = a.x; wr[4*j+1] = a.y; wr[4*j+2] = a.z; wr[4*j+3] = a.w;
            wz[4*j+0] = c.x; wz[4*j+1] = c.y; wz[4*j+2] = c.z; wz[4*j+3] = c.w;
            wn[4*j+0] = d.x; wn[4*j+1] = d.y; wn[4*j+2] = d.z; wn[4*j+3] = d.w;
        }
    }
    const float ur0 = Wih[3*k+0],      ur1 = Wih[3*k+1],      ur2 = Wih[3*k+2];
    const float uz0 = Wih[3*(32+k)+0], uz1 = Wih[3*(32+k)+1], uz2 = Wih[3*(32+k)+2];
    const float un0 = Wih[3*(64+k)+0], un1 = Wih[3*(64+k)+1], un2 = Wih[3*(64+k)+2];
    const float br  = Bih[k]      + Bhh[k];
    const float bz  = Bih[32 + k] + Bhh[32 + k];
    const float bin = Bih[64 + k];
    const float bhn = Bhh[64 + k];
    const float fcw = fc_w[dir * 32 + k];

    // ---- h state: LDS ping-pong, 16 rows x 32 floats per buffer ----
    __shared__ float sh[2][16][32];
    sh[0][bloc0    ][k] = 0.0f;
    sh[0][bloc0 + 1][k] = 0.0f;
    float hk0 = 0.0f, hk1 = 0.0f;

    // x[t][b][i] = x[(t*BB + b)*3 + i]
    const float* xb = x + (size_t)b0 * 3;
    {
        // prime x for step 0
    }
    int t_first = dir ? (TT - 1) : 0;
    size_t xo0 = (size_t)t_first * (BB * 3);
    float x00 = xb[xo0 + 0], x01 = xb[xo0 + 1], x02 = xb[xo0 + 2];
    float x10 = xb[xo0 + 3], x11 = xb[xo0 + 4], x12 = xb[xo0 + 5];

    __syncthreads();

    for (int t = 0; t < TT; ++t) {
        // software-prefetch next step's x (clamped index; unused garbage at t=T-1)
        int tn = dir ? (TT - 2 - t) : (t + 1);
        tn = tn < 0 ? 0 : (tn > TT - 1 ? TT - 1 : tn);
        size_t xo = (size_t)tn * (BB * 3);
        float nx00 = xb[xo + 0], nx01 = xb[xo + 1], nx02 = xb[xo + 2];
        float nx10 = xb[xo + 3], nx11 = xb[xo + 4], nx12 = xb[xo + 5];

        const float* h0row = sh[t & 1][bloc0];
        const float* h1row = sh[t & 1][bloc0 + 1];

        float hr0 = 0.f, hz0 = 0.f, hn0 = 0.f;
        float hr1 = 0.f, hz1 = 0.f, hn1 = 0.f;
        #pragma unroll
        for (int j = 0; j < 8; ++j) {
            const float4 a = ((const float4*)h0row)[j];
            hr0 = fmaf(wr[4*j+0], a.x, hr0); hr0 = fmaf(wr[4*j+1], a.y, hr0);
            hr0 = fmaf(wr[4*j+2], a.z, hr0); hr0 = fmaf(wr[4*j+3], a.w, hr0);
            hz0 = fmaf(wz[4*j+0], a.x, hz0); hz0 = fmaf(wz[4*j+1], a.y, hz0);
            hz0 = fmaf(wz[4*j+2], a.z, hz0); hz0 = fmaf(wz[4*j+3], a.w, hz0);
            hn0 = fmaf(wn[4*j+0], a.x, hn0); hn0 = fmaf(wn[4*j+1], a.y, hn0);
            hn0 = fmaf(wn[4*j+2], a.z, hn0); hn0 = fmaf(wn[4*j+3], a.w, hn0);
            const float4 c = ((const float4*)h1row)[j];
            hr1 = fmaf(wr[4*j+0], c.x, hr1); hr1 = fmaf(wr[4*j+1], c.y, hr1);
            hr1 = fmaf(wr[4*j+2], c.z, hr1); hr1 = fmaf(wr[4*j+3], c.w, hr1);
            hz1 = fmaf(wz[4*j+0], c.x, hz1); hz1 = fmaf(wz[4*j+1], c.y, hz1);
            hz1 = fmaf(wz[4*j+2], c.z, hz1); hz1 = fmaf(wz[4*j+3], c.w, hz1);
            hn1 = fmaf(wn[4*j+0], c.x, hn1); hn1 = fmaf(wn[4*j+1], c.y, hn1);
            hn1 = fmaf(wn[4*j+2], c.z, hn1); hn1 = fmaf(wn[4*j+3], c.w, hn1);
        }

        // gates, batch row 0
        {
            float xr = fmaf(ur0, x00, fmaf(ur1, x01, ur2 * x02));
            float xz = fmaf(uz0, x00, fmaf(uz1, x01, uz2 * x02));
            float xn = fmaf(un0, x00, fmaf(un1, x01, un2 * x02));
            float r = fsigmoid(xr + hr0 + br);
            float z = fsigmoid(xz + hz0 + bz);
            float n = ftanh_fast(xn + bin + r * (hn0 + bhn));
            hk0 = fmaf(z, hk0 - n, n);      // (1-z)*n + z*h
        }
        // gates, batch row 1
        {
            float xr = fmaf(ur0, x10, fmaf(ur1, x11, ur2 * x12));
            float xz = fmaf(uz0, x10, fmaf(uz1, x11, uz2 * x12));
            float xn = fmaf(un0, x10, fmaf(un1, x11, un2 * x12));
            float r = fsigmoid(xr + hr1 + br);
            float z = fsigmoid(xz + hz1 + bz);
            float n = ftanh_fast(xn + bin + r * (hn1 + bhn));
            hk1 = fmaf(z, hk1 - n, n);
        }

        sh[(t + 1) & 1][bloc0    ][k] = hk0;
        sh[(t + 1) & 1][bloc0 + 1][k] = hk1;

        // fused FC: p = sum_k fcw[k]*h_new[k] per batch row, half-wave butterfly
        float p0 = fcw * hk0;
        float p1 = fcw * hk1;
        #pragma unroll
        for (int m = 1; m < 32; m <<= 1) {
            p0 += __shfl_xor(p0, m, 64);
            p1 += __shfl_xor(p1, m, 64);
        }
        if (k == 0) {
            int to = dir ? (TT - 1 - t) : t;
            atomicAdd(&out[(size_t)to * BB + b0    ], p0);
            atomicAdd(&out[(size_t)to * BB + b0 + 1], p1);
        }

        x00 = nx00; x01 = nx01; x02 = nx02;
        x10 = nx10; x11 = nx11; x12 = nx12;
        __syncthreads();
    }
}

extern "C" void kernel_launch(void* const* d_in, const int* in_sizes, int n_in,
                              void* d_out, int out_size, void* d_ws, size_t ws_size,
                              hipStream_t stream) {
    const float* x      = (const float*)d_in[0];
    const float* w_ih_f = (const float*)d_in[1];
    const float* w_hh_f = (const float*)d_in[2];
    const float* b_ih_f = (const float*)d_in[3];
    const float* b_hh_f = (const float*)d_in[4];
    const float* w_ih_b = (const float*)d_in[5];
    const float* w_hh_b = (const float*)d_in[6];
    const float* b_ih_b = (const float*)d_in[7];
    const float* b_hh_b = (const float*)d_in[8];
    const float* fc_w   = (const float*)d_in[9];
    const float* fc_b   = (const float*)d_in[10];
    float* out = (float*)d_out;

    // init out with fc_b (atomic accumulation target for both directions)
    gru_init_out<<<(TT * BB / 4 + 255) / 256, 256, 0, stream>>>(out, fc_b);

    dim3 grid(BB / 16, 2);
    gru_scan_kernel<<<grid, 256, 0, stream>>>(
        x, w_ih_f, w_hh_f, b_ih_f, b_hh_f,
        w_ih_b, w_hh_b, b_ih_b, b_hh_b, fc_w, out);
}

// Round 2
// 347.177 us; speedup vs baseline: 1.0501x; 1.0501x over previous
//
#include <hip/hip_runtime.h>

#define TT 200
#define BB 4096
#define HH 32

__device__ __forceinline__ float fsigmoid(float x) {
    return __fdividef(1.0f, 1.0f + __expf(-x));
}
__device__ __forceinline__ float ftanh_fast(float x) {
    // tanh(x) = 1 - 2/(exp(2x)+1); saturates correctly for |x| large
    return 1.0f - __fdividef(2.0f, 1.0f + __expf(2.0f * x));
}

// Fill out[T*B] with fc_b[0]; grid sized exactly TT*BB/4 threads, float4 stores.
__global__ void gru_init_out(float* __restrict__ out, const float* __restrict__ fc_b) {
    int i = blockIdx.x * blockDim.x + threadIdx.x;
    float v = fc_b[0];
    ((float4*)out)[i] = make_float4(v, v, v, v);
}

// Persistent GRU scan. Thread (k, b-pair) owns hidden unit k for two batch rows,
// holds w_hh rows {k, 32+k, 64+k} in 96 VGPRs (pinned via inline asm — round 1
// showed the backend spills ~half to scratch otherwise: WRITE_SIZE 25.6MB, VGPR=84),
// h shared via LDS. Sharing is intra-half-wave only -> NO __syncthreads, NO ping-pong.
// Block = 256 threads = 4 waves = 16 batch rows; grid = (B/16, 2 dirs).
__global__ __launch_bounds__(256, 2) void gru_scan_kernel(
    const float* __restrict__ x,
    const float* __restrict__ w_ih_f, const float* __restrict__ w_hh_f,
    const float* __restrict__ b_ih_f, const float* __restrict__ b_hh_f,
    const float* __restrict__ w_ih_b, const float* __restrict__ w_hh_b,
    const float* __restrict__ b_ih_b, const float* __restrict__ b_hh_b,
    const float* __restrict__ fc_w,
    float* __restrict__ out)
{
    const int dir   = blockIdx.y;
    const int lane  = threadIdx.x & 63;
    const int wv    = threadIdx.x >> 6;   // wave in block: 0..3
    const int k     = lane & 31;          // hidden unit
    const int half  = lane >> 5;          // half-wave: 0/1
    const int bloc0 = wv * 4 + half * 2;  // 0..14 (even)
    const int b0    = blockIdx.x * 16 + bloc0;

    const float* __restrict__ Wih = dir ? w_ih_b : w_ih_f;
    const float* __restrict__ Whh = dir ? w_hh_b : w_hh_f;
    const float* __restrict__ Bih = dir ? b_ih_b : b_ih_f;
    const float* __restrict__ Bhh = dir ? b_hh_b : b_hh_f;

    // ---- weight-stationary registers: rows k, 32+k, 64+k of w_hh [96x32] ----
    float wr[32], wz[32], wn[32];
    {
        const float4* W4 = (const float4*)Whh;   // rows are 128B aligned
        #pragma unroll
        for (int j = 0; j < 8; ++j) {
            float4 a = W4[(k)      * 8 + j];
            float4 c = W4[(32 + k) * 8 + j];
            float4 d = W4[(64 + k) * 8 + j];
            wr[4*j+0] = a.x; wr[4*j+1] = a.y; wr[4*j+2] = a.z; wr[4*j+3] = a.w;
            wz[4*j+0] = c.x; wz[4*j+1] = c.y; wz[4*j+2] = c.z; wz[4*j+3] = c.w;
            wn[4*j+0] = d.x; wn[4*j+1] = d.y; wn[4*j+2] = d.z; wn[4*j+3] = d.w;
        }
    }
    // Pin all 96 weights into VGPRs: opaque to the optimizer -> cannot be
    // rematerialized / sunk back to memory / spilled-by-choice.
    #pragma unroll
    for (int j = 0; j < 32; ++j) {
        asm volatile("" : "+v"(wr[j]), "+v"(wz[j]), "+v"(wn[j]));
    }

    const float ur0 = Wih[3*k+0],      ur1 = Wih[3*k+1],      ur2 = Wih[3*k+2];
    const float uz0 = Wih[3*(32+k)+0], uz1 = Wih[3*(32+k)+1], uz2 = Wih[3*(32+k)+2];
    const float un0 = Wih[3*(64+k)+0], un1 = Wih[3*(64+k)+1], un2 = Wih[3*(64+k)+2];
    const float br  = Bih[k]      + Bhh[k];
    const float bz  = Bih[32 + k] + Bhh[32 + k];
    const float bin = Bih[64 + k];
    const float bhn = Bhh[64 + k];
    const float fcw = fc_w[dir * 32 + k];

    // ---- h state: single LDS buffer, rows owned exclusively per half-wave ----
    __shared__ float sh[16][32];
    sh[bloc0    ][k] = 0.0f;
    sh[bloc0 + 1][k] = 0.0f;
    float hk0 = 0.0f, hk1 = 0.0f;

    // x[t][b][i] = x[(t*BB + b)*3 + i]; pointer-walk in time
    const int t_first = dir ? (TT - 1) : 0;
    const long xstep  = dir ? -(long)(BB * 3) : (long)(BB * 3);
    const long ostep  = dir ? -(long)BB : (long)BB;
    const float* xp = x + (size_t)t_first * (BB * 3) + (size_t)b0 * 3;
    float* op = out + (size_t)t_first * BB + b0;

    float x00, x01, x02, x10, x11, x12;
    {
        const float2* q = (const float2*)xp;
        float2 a0 = q[0], a1 = q[1], a2 = q[2];
        x00 = a0.x; x01 = a0.y; x02 = a1.x;
        x10 = a1.y; x11 = a2.x; x12 = a2.y;
    }

    for (int t = 0; t < TT; ++t) {
        // software-prefetch next step's x (clamped pointer on last iter)
        const float* xpn = (t < TT - 1) ? (xp + xstep) : xp;
        float nx00, nx01, nx02, nx10, nx11, nx12;
        {
            const float2* q = (const float2*)xpn;
            float2 a0 = q[0], a1 = q[1], a2 = q[2];
            nx00 = a0.x; nx01 = a0.y; nx02 = a1.x;
            nx10 = a1.y; nx11 = a2.x; nx12 = a2.y;
        }
        xp = xpn;

        const float* h0row = sh[bloc0];
        const float* h1row = sh[bloc0 + 1];

        float hr0 = 0.f, hz0 = 0.f, hn0 = 0.f;
        float hr1 = 0.f, hz1 = 0.f, hn1 = 0.f;
        #pragma unroll
        for (int j = 0; j < 8; ++j) {
            const float4 a = ((const float4*)h0row)[j];
            hr0 = fmaf(wr[4*j+0], a.x, hr0); hr0 = fmaf(wr[4*j+1], a.y, hr0);
            hr0 = fmaf(wr[4*j+2], a.z, hr0); hr0 = fmaf(wr[4*j+3], a.w, hr0);
            hz0 = fmaf(wz[4*j+0], a.x, hz0); hz0 = fmaf(wz[4*j+1], a.y, hz0);
            hz0 = fmaf(wz[4*j+2], a.z, hz0); hz0 = fmaf(wz[4*j+3], a.w, hz0);
            hn0 = fmaf(wn[4*j+0], a.x, hn0); hn0 = fmaf(wn[4*j+1], a.y, hn0);
            hn0 = fmaf(wn[4*j+2], a.z, hn0); hn0 = fmaf(wn[4*j+3], a.w, hn0);
            const float4 c = ((const float4*)h1row)[j];
            hr1 = fmaf(wr[4*j+0], c.x, hr1); hr1 = fmaf(wr[4*j+1], c.y, hr1);
            hr1 = fmaf(wr[4*j+2], c.z, hr1); hr1 = fmaf(wr[4*j+3], c.w, hr1);
            hz1 = fmaf(wz[4*j+0], c.x, hz1); hz1 = fmaf(wz[4*j+1], c.y, hz1);
            hz1 = fmaf(wz[4*j+2], c.z, hz1); hz1 = fmaf(wz[4*j+3], c.w, hz1);
            hn1 = fmaf(wn[4*j+0], c.x, hn1); hn1 = fmaf(wn[4*j+1], c.y, hn1);
            hn1 = fmaf(wn[4*j+2], c.z, hn1); hn1 = fmaf(wn[4*j+3], c.w, hn1);
        }

        // gates, batch row 0
        {
            float xr = fmaf(ur0, x00, fmaf(ur1, x01, ur2 * x02));
            float xz = fmaf(uz0, x00, fmaf(uz1, x01, uz2 * x02));
            float xn = fmaf(un0, x00, fmaf(un1, x01, un2 * x02));
            float r = fsigmoid(xr + hr0 + br);
            float z = fsigmoid(xz + hz0 + bz);
            float n = ftanh_fast(xn + bin + r * (hn0 + bhn));
            hk0 = fmaf(z, hk0 - n, n);      // (1-z)*n + z*h
        }
        // gates, batch row 1
        {
            float xr = fmaf(ur0, x10, fmaf(ur1, x11, ur2 * x12));
            float xz = fmaf(uz0, x10, fmaf(uz1, x11, uz2 * x12));
            float xn = fmaf(un0, x10, fmaf(un1, x11, un2 * x12));
            float r = fsigmoid(xr + hr1 + br);
            float z = fsigmoid(xz + hz1 + bz);
            float n = ftanh_fast(xn + bin + r * (hn1 + bhn));
            hk1 = fmaf(z, hk1 - n, n);
        }

        // intra-wave LDS update: DS ops are instruction-ordered within a wave,
        // rows are half-wave-private -> no barrier needed.
        sh[bloc0    ][k] = hk0;
        sh[bloc0 + 1][k] = hk1;

        // fused FC: p = sum_k fcw[k]*h_new[k] per batch row, half-wave butterfly
        float p0 = fcw * hk0;
        float p1 = fcw * hk1;
        #pragma unroll
        for (int m = 1; m < 32; m <<= 1) {
            p0 += __shfl_xor(p0, m, 64);
            p1 += __shfl_xor(p1, m, 64);
        }
        if (k == 0) {
            atomicAdd(op,     p0);
            atomicAdd(op + 1, p1);
        }
        op += ostep;

        x00 = nx00; x01 = nx01; x02 = nx02;
        x10 = nx10; x11 = nx11; x12 = nx12;
    }
}

extern "C" void kernel_launch(void* const* d_in, const int* in_sizes, int n_in,
                              void* d_out, int out_size, void* d_ws, size_t ws_size,
                              hipStream_t stream) {
    const float* x      = (const float*)d_in[0];
    const float* w_ih_f = (const float*)d_in[1];
    const float* w_hh_f = (const float*)d_in[2];
    const float* b_ih_f = (const float*)d_in[3];
    const float* b_hh_f = (const float*)d_in[4];
    const float* w_ih_b = (const float*)d_in[5];
    const float* w_hh_b = (const float*)d_in[6];
    const float* b_ih_b = (const float*)d_in[7];
    const float* b_hh_b = (const float*)d_in[8];
    const float* fc_w   = (const float*)d_in[9];
    const float* fc_b   = (const float*)d_in[10];
    float* out = (float*)d_out;

    // init out with fc_b (atomic accumulation target for both directions)
    gru_init_out<<<(TT * BB / 4 + 255) / 256, 256, 0, stream>>>(out, fc_b);

    dim3 grid(BB / 16, 2);
    gru_scan_kernel<<<grid, 256, 0, stream>>>(
        x, w_ih_f, w_hh_f, b_ih_f, b_hh_f,
        w_ih_b, w_hh_b, b_ih_b, b_hh_b, fc_w, out);
}

// Round 3
// 322.278 us; speedup vs baseline: 1.1313x; 1.0773x over previous
//
#include <hip/hip_runtime.h>

#define TT 200
#define BB 4096
#define HH 32

__device__ __forceinline__ float fsigmoid(float x) {
    return __fdividef(1.0f, 1.0f + __expf(-x));
}
__device__ __forceinline__ float ftanh_fast(float x) {
    // tanh(x) = 1 - 2/(exp(2x)+1); saturates correctly for |x| large
    return 1.0f - __fdividef(2.0f, 1.0f + __expf(2.0f * x));
}

// Fill out[T*B] with fc_b[0]; grid sized exactly TT*BB/4 threads, float4 stores.
__global__ void gru_init_out(float* __restrict__ out, const float* __restrict__ fc_b) {
    int i = blockIdx.x * blockDim.x + threadIdx.x;
    float v = fc_b[0];
    ((float4*)out)[i] = make_float4(v, v, v, v);
}

// Persistent GRU scan. Thread (k, b-pair) owns hidden unit k for two batch rows,
// holds w_hh rows {k, 32+k, 64+k} in registers, h shared via LDS (intra-half-wave
// only -> no __syncthreads, no ping-pong). The fused-FC reduction is computed as
// a 4th dot product over the SAME LDS float4 reads with fc_w held in SGPRs
// (wave-uniform) -- this replaces the 10-deep serial shuffle butterfly of r1/r2.
// FC(h_{t-1}) falls out of step t's reads -> store lagged by one; epilogue pass
// emits out[T-1]. Block = 256 threads = 4 waves = 16 batch rows; grid (B/16, 2).
__global__ __launch_bounds__(256, 2) void gru_scan_kernel(
    const float* __restrict__ x,
    const float* __restrict__ w_ih_f, const float* __restrict__ w_hh_f,
    const float* __restrict__ b_ih_f, const float* __restrict__ b_hh_f,
    const float* __restrict__ w_ih_b, const float* __restrict__ w_hh_b,
    const float* __restrict__ b_ih_b, const float* __restrict__ b_hh_b,
    const float* __restrict__ fc_w,
    float* __restrict__ out)
{
    const int dir   = blockIdx.y;
    const int lane  = threadIdx.x & 63;
    const int wv    = threadIdx.x >> 6;   // wave in block: 0..3
    const int k     = lane & 31;          // hidden unit
    const int half  = lane >> 5;          // half-wave: 0/1
    const int bloc0 = wv * 4 + half * 2;  // 0..14 (even)
    const int b0    = blockIdx.x * 16 + bloc0;

    const float* __restrict__ Wih = dir ? w_ih_b : w_ih_f;
    const float* __restrict__ Whh = dir ? w_hh_b : w_hh_f;
    const float* __restrict__ Bih = dir ? b_ih_b : b_ih_f;
    const float* __restrict__ Bhh = dir ? b_hh_b : b_hh_f;

    // ---- weight-stationary registers: rows k, 32+k, 64+k of w_hh [96x32] ----
    float wr[32], wz[32], wn[32];
    {
        const float4* W4 = (const float4*)Whh;   // rows are 128B aligned
        #pragma unroll
        for (int j = 0; j < 8; ++j) {
            float4 a = W4[(k)      * 8 + j];
            float4 c = W4[(32 + k) * 8 + j];
            float4 d = W4[(64 + k) * 8 + j];
            wr[4*j+0] = a.x; wr[4*j+1] = a.y; wr[4*j+2] = a.z; wr[4*j+3] = a.w;
            wz[4*j+0] = c.x; wz[4*j+1] = c.y; wz[4*j+2] = c.z; wz[4*j+3] = c.w;
            wn[4*j+0] = d.x; wn[4*j+1] = d.y; wn[4*j+2] = d.z; wn[4*j+3] = d.w;
        }
    }

    const float ur0 = Wih[3*k+0],      ur1 = Wih[3*k+1],      ur2 = Wih[3*k+2];
    const float uz0 = Wih[3*(32+k)+0], uz1 = Wih[3*(32+k)+1], uz2 = Wih[3*(32+k)+2];
    const float un0 = Wih[3*(64+k)+0], un1 = Wih[3*(64+k)+1], un2 = Wih[3*(64+k)+2];
    const float br  = Bih[k]      + Bhh[k];
    const float bz  = Bih[32 + k] + Bhh[32 + k];
    const float bin = Bih[64 + k];
    const float bhn = Bhh[64 + k];

    // fc weights: wave-uniform indices -> scalar loads, live in SGPRs
    float fcs[32];
    #pragma unroll
    for (int j = 0; j < 32; ++j) fcs[j] = fc_w[dir * 32 + j];

    // ---- h state: single LDS buffer, rows owned exclusively per half-wave ----
    __shared__ float sh[16][32];
    sh[bloc0    ][k] = 0.0f;
    sh[bloc0 + 1][k] = 0.0f;
    float hk0 = 0.0f, hk1 = 0.0f;

    // x[t][b][i] = x[(t*BB + b)*3 + i]; pointer-walk in time
    const int t_first = dir ? (TT - 1) : 0;
    const long xstep  = dir ? -(long)(BB * 3) : (long)(BB * 3);
    const long ostep  = dir ? -(long)BB : (long)BB;
    const float* xp = x + (size_t)t_first * (BB * 3) + (size_t)b0 * 3;
    float* op = out + (size_t)t_first * BB + b0;

    float x00, x01, x02, x10, x11, x12;
    {
        const float2* q = (const float2*)xp;
        float2 a0 = q[0], a1 = q[1], a2 = q[2];
        x00 = a0.x; x01 = a0.y; x02 = a1.x;
        x10 = a1.y; x11 = a2.x; x12 = a2.y;
    }

    for (int t = 0; t < TT; ++t) {
        // software-prefetch next step's x (clamped pointer on last iter)
        const float* xpn = (t < TT - 1) ? (xp + xstep) : xp;
        float nx00, nx01, nx02, nx10, nx11, nx12;
        {
            const float2* q = (const float2*)xpn;
            float2 a0 = q[0], a1 = q[1], a2 = q[2];
            nx00 = a0.x; nx01 = a0.y; nx02 = a1.x;
            nx10 = a1.y; nx11 = a2.x; nx12 = a2.y;
        }
        xp = xpn;

        const float* h0row = sh[bloc0];
        const float* h1row = sh[bloc0 + 1];

        float hr0 = 0.f, hz0 = 0.f, hn0 = 0.f, p0 = 0.f;
        float hr1 = 0.f, hz1 = 0.f, hn1 = 0.f, p1 = 0.f;
        #pragma unroll
        for (int j = 0; j < 8; ++j) {
            const float4 a = ((const float4*)h0row)[j];
            hr0 = fmaf(wr[4*j+0], a.x, hr0); hr0 = fmaf(wr[4*j+1], a.y, hr0);
            hr0 = fmaf(wr[4*j+2], a.z, hr0); hr0 = fmaf(wr[4*j+3], a.w, hr0);
            hz0 = fmaf(wz[4*j+0], a.x, hz0); hz0 = fmaf(wz[4*j+1], a.y, hz0);
            hz0 = fmaf(wz[4*j+2], a.z, hz0); hz0 = fmaf(wz[4*j+3], a.w, hz0);
            hn0 = fmaf(wn[4*j+0], a.x, hn0); hn0 = fmaf(wn[4*j+1], a.y, hn0);
            hn0 = fmaf(wn[4*j+2], a.z, hn0); hn0 = fmaf(wn[4*j+3], a.w, hn0);
            p0  = fmaf(fcs[4*j+0], a.x, p0); p0  = fmaf(fcs[4*j+1], a.y, p0);
            p0  = fmaf(fcs[4*j+2], a.z, p0); p0  = fmaf(fcs[4*j+3], a.w, p0);
            const float4 c = ((const float4*)h1row)[j];
            hr1 = fmaf(wr[4*j+0], c.x, hr1); hr1 = fmaf(wr[4*j+1], c.y, hr1);
            hr1 = fmaf(wr[4*j+2], c.z, hr1); hr1 = fmaf(wr[4*j+3], c.w, hr1);
            hz1 = fmaf(wz[4*j+0], c.x, hz1); hz1 = fmaf(wz[4*j+1], c.y, hz1);
            hz1 = fmaf(wz[4*j+2], c.z, hz1); hz1 = fmaf(wz[4*j+3], c.w, hz1);
            hn1 = fmaf(wn[4*j+0], c.x, hn1); hn1 = fmaf(wn[4*j+1], c.y, hn1);
            hn1 = fmaf(wn[4*j+2], c.z, hn1); hn1 = fmaf(wn[4*j+3], c.w, hn1);
            p1  = fmaf(fcs[4*j+0], c.x, p1); p1  = fmaf(fcs[4*j+1], c.y, p1);
            p1  = fmaf(fcs[4*j+2], c.z, p1); p1  = fmaf(fcs[4*j+3], c.w, p1);
        }

        // lagged fused-FC store: p is fc(h_{t-1}) -> out row t-1
        if (t > 0 && k < 2) {
            atomicAdd(op - ostep + k, k ? p1 : p0);
        }

        // gates, batch row 0
        {
            float xr = fmaf(ur0, x00, fmaf(ur1, x01, ur2 * x02));
            float xz = fmaf(uz0, x00, fmaf(uz1, x01, uz2 * x02));
            float xn = fmaf(un0, x00, fmaf(un1, x01, un2 * x02));
            float r = fsigmoid(xr + hr0 + br);
            float z = fsigmoid(xz + hz0 + bz);
            float n = ftanh_fast(xn + bin + r * (hn0 + bhn));
            hk0 = fmaf(z, hk0 - n, n);      // (1-z)*n + z*h
        }
        // gates, batch row 1
        {
            float xr = fmaf(ur0, x10, fmaf(ur1, x11, ur2 * x12));
            float xz = fmaf(uz0, x10, fmaf(uz1, x11, uz2 * x12));
            float xn = fmaf(un0, x10, fmaf(un1, x11, un2 * x12));
            float r = fsigmoid(xr + hr1 + br);
            float z = fsigmoid(xz + hz1 + bz);
            float n = ftanh_fast(xn + bin + r * (hn1 + bhn));
            hk1 = fmaf(z, hk1 - n, n);
        }

        // intra-wave LDS update: DS ops are instruction-ordered within a wave,
        // rows are half-wave-private -> no barrier needed.
        sh[bloc0    ][k] = hk0;
        sh[bloc0 + 1][k] = hk1;

        x00 = nx00; x01 = nx01; x02 = nx02;
        x10 = nx10; x11 = nx11; x12 = nx12;
        op += ostep;
    }

    // epilogue: emit out row TT-1 from the final h state in LDS
    {
        const float* h0row = sh[bloc0];
        const float* h1row = sh[bloc0 + 1];
        float p0 = 0.f, p1 = 0.f;
        #pragma unroll
        for (int j = 0; j < 8; ++j) {
            const float4 a = ((const float4*)h0row)[j];
            p0 = fmaf(fcs[4*j+0], a.x, p0); p0 = fmaf(fcs[4*j+1], a.y, p0);
            p0 = fmaf(fcs[4*j+2], a.z, p0); p0 = fmaf(fcs[4*j+3], a.w, p0);
            const float4 c = ((const float4*)h1row)[j];
            p1 = fmaf(fcs[4*j+0], c.x, p1); p1 = fmaf(fcs[4*j+1], c.y, p1);
            p1 = fmaf(fcs[4*j+2], c.z, p1); p1 = fmaf(fcs[4*j+3], c.w, p1);
        }
        if (k < 2) {
            atomicAdd(op - ostep + k, k ? p1 : p0);
        }
    }
}

extern "C" void kernel_launch(void* const* d_in, const int* in_sizes, int n_in,
                              void* d_out, int out_size, void* d_ws, size_t ws_size,
                              hipStream_t stream) {
    const float* x      = (const float*)d_in[0];
    const float* w_ih_f = (const float*)d_in[1];
    const float* w_hh_f = (const float*)d_in[2];
    const float* b_ih_f = (const float*)d_in[3];
    const float* b_hh_f = (const float*)d_in[4];
    const float* w_ih_b = (const float*)d_in[5];
    const float* w_hh_b = (const float*)d_in[6];
    const float* b_ih_b = (const float*)d_in[7];
    const float* b_hh_b = (const float*)d_in[8];
    const float* fc_w   = (const float*)d_in[9];
    const float* fc_b   = (const float*)d_in[10];
    float* out = (float*)d_out;

    // init out with fc_b (atomic accumulation target for both directions)
    gru_init_out<<<(TT * BB / 4 + 255) / 256, 256, 0, stream>>>(out, fc_b);

    dim3 grid(BB / 16, 2);
    gru_scan_kernel<<<grid, 256, 0, stream>>>(
        x, w_ih_f, w_hh_f, b_ih_f, b_hh_f,
        w_ih_b, w_hh_b, b_ih_b, b_hh_b, fc_w, out);
}

// Round 4
// 296.501 us; speedup vs baseline: 1.2296x; 1.0869x over previous
//
#include <hip/hip_runtime.h>

#define TT 200
#define BB 4096
#define HH 32

typedef __bf16 bf16x8 __attribute__((ext_vector_type(8)));
typedef float  f32x4  __attribute__((ext_vector_type(4)));

__device__ __forceinline__ float fsigmoid(float x) {
    return __fdividef(1.0f, 1.0f + __expf(-x));
}
__device__ __forceinline__ float ftanh_fast(float x) {
    return 1.0f - __fdividef(2.0f, 1.0f + __expf(2.0f * x));
}

// Fill out[T*B] with fc_b[0]; atomic accumulation target for both directions.
__global__ void gru_init_out(float* __restrict__ out, const float* __restrict__ fc_b) {
    int i = blockIdx.x * blockDim.x + threadIdx.x;
    float v = fc_b[0];
    ((float4*)out)[i] = make_float4(v, v, v, v);
}

// MFMA GRU scan. One wave owns 16 batch rows of one direction.
// Per step: 7 h-MFMAs (6 gate tiles + fc tile, biases via C operand) +
// 6 x-MFMAs (K rows >=3 zero in B, x fed from prefetch regs, no LDS).
// D layout (col=lane&15, row=quad*4+reg) gives each lane gates r/z/n for
// units {c0, c0+16} x 4 rows locally (96 = 6*16, gate offset 32 = 2*16).
// h stays fp32 in regs; only the MFMA A-input round-trips LDS as bf16.
// Intra-wave LDS only -> no barriers. Block = 2 waves; grid = 256 blocks.
__global__ __launch_bounds__(128, 1) void gru_mfma_kernel(
    const float* __restrict__ x,
    const float* __restrict__ w_ih_f, const float* __restrict__ w_hh_f,
    const float* __restrict__ b_ih_f, const float* __restrict__ b_hh_f,
    const float* __restrict__ w_ih_b, const float* __restrict__ w_hh_b,
    const float* __restrict__ b_ih_b, const float* __restrict__ b_hh_b,
    const float* __restrict__ fc_w,
    float* __restrict__ out)
{
    const int wv   = threadIdx.x >> 6;
    const int lane = threadIdx.x & 63;
    const int c0   = lane & 15;          // D col / A row / B col
    const int q    = lane >> 4;          // quad: D rows 4q..4q+3, A/B k-chunk q*8..
    const int wave_id = blockIdx.x * 2 + wv;
    const int dir  = wave_id >> 8;       // 256 tiles per dir
    const int b0   = (wave_id & 255) * 16;

    const float* __restrict__ Wih = dir ? w_ih_b : w_ih_f;
    const float* __restrict__ Whh = dir ? w_hh_b : w_hh_f;
    const float* __restrict__ Bih = dir ? b_ih_b : b_ih_f;
    const float* __restrict__ Bhh = dir ? b_hh_b : b_hh_f;

    // ---- static B fragments + bias C fragments ----
    // h-part: tile tt covers gate cols [16tt,16tt+16); lane col g = 16tt + c0.
    // B[k][n] = Whh[g][k], k = q*8 + j.
    bf16x8 Bh[7];
    f32x4  Ch[7];
    #pragma unroll
    for (int tt = 0; tt < 6; ++tt) {
        int g = 16 * tt + c0;
        const float* wrow = Whh + g * 32 + q * 8;
        #pragma unroll
        for (int j = 0; j < 8; ++j) Bh[tt][j] = (__bf16)wrow[j];
        float bb = Bhh[g];
        Ch[tt][0] = bb; Ch[tt][1] = bb; Ch[tt][2] = bb; Ch[tt][3] = bb;
    }
    // fc tile: col 0 only = fc_w (applies to h); C = 0 (fc_b handled by init).
    #pragma unroll
    for (int j = 0; j < 8; ++j)
        Bh[6][j] = (c0 == 0) ? (__bf16)fc_w[dir * 32 + q * 8 + j] : (__bf16)0.0f;
    Ch[6][0] = 0.f; Ch[6][1] = 0.f; Ch[6][2] = 0.f; Ch[6][3] = 0.f;

    // x-part: B[k][n] = (k<3) ? Wih[g][k] : 0  (rows k>=3 zero => A-garbage safe)
    bf16x8 Bx[6];
    f32x4  Cx[6];
    #pragma unroll
    for (int tt = 0; tt < 6; ++tt) {
        int g = 16 * tt + c0;
        #pragma unroll
        for (int j = 0; j < 8; ++j)
            Bx[tt][j] = (q == 0 && j < 3) ? (__bf16)Wih[g * 3 + j] : (__bf16)0.0f;
        float bb = Bih[g];
        Cx[tt][0] = bb; Cx[tt][1] = bb; Cx[tt][2] = bb; Cx[tt][3] = bb;
    }

    // ---- h state: fp32 in regs (layout step-invariant), bf16 tile in LDS ----
    float h0[4] = {0.f, 0.f, 0.f, 0.f};   // unit c0,     rows 4q+i
    float h1[4] = {0.f, 0.f, 0.f, 0.f};   // unit c0+16,  rows 4q+i
    __shared__ __bf16 sh[2][16][40];      // row stride 80 B: b128-aligned, conflict-light
    #pragma unroll
    for (int i = 0; i < 4; ++i) {
        sh[wv][4 * q + i][c0]      = (__bf16)0.0f;
        sh[wv][4 * q + i][c0 + 16] = (__bf16)0.0f;
    }

    // x pointer-walk: lane loads x[t][b0+c0][0..2] (q-duplicated -> broadcast)
    const int  t_first = dir ? (TT - 1) : 0;
    const long xstep   = dir ? -(long)(BB * 3) : (long)(BB * 3);
    const long ostep   = dir ? -(long)BB : (long)BB;
    const float* xp = x + (size_t)t_first * (BB * 3) + (size_t)(b0 + c0) * 3;
    float* ocur = out + (size_t)t_first * BB + b0;

    float xa = xp[0], xb = xp[1], xc = xp[2];

    for (int t = 0; t < TT; ++t) {
        // x A-fragment from regs; lanes q>0 contribute k>=8 rows (B zero there)
        bf16x8 Ax;
        Ax[0] = (__bf16)xa; Ax[1] = (__bf16)xb; Ax[2] = (__bf16)xc;
        Ax[3] = (__bf16)0.0f; Ax[4] = (__bf16)0.0f; Ax[5] = (__bf16)0.0f;
        Ax[6] = (__bf16)0.0f; Ax[7] = (__bf16)0.0f;

        // h A-fragment: lane reads row c0, k = q*8..q*8+7 (one ds_read_b128)
        bf16x8 Ah = *(const bf16x8*)&sh[wv][c0][q * 8];

        // prefetch next x
        const float* xpn = (t < TT - 1) ? (xp + xstep) : xp;
        float nxa = xpn[0], nxb = xpn[1], nxc = xpn[2];
        xp = xpn;

        // x-MFMAs first (independent of the ds_read)
        f32x4 Dx[6];
        #pragma unroll
        for (int tt = 0; tt < 6; ++tt)
            Dx[tt] = __builtin_amdgcn_mfma_f32_16x16x32_bf16(Ax, Bx[tt], Cx[tt], 0, 0, 0);
        f32x4 Dh[7];
        #pragma unroll
        for (int tt = 0; tt < 7; ++tt)
            Dh[tt] = __builtin_amdgcn_mfma_f32_16x16x32_bf16(Ah, Bh[tt], Ch[tt], 0, 0, 0);

        // lagged fused-FC: Dh[6] = fc(h_t) = out contribution for time t-1
        if (t > 0 && c0 == 0) {
            float* oprev = ocur - ostep;
            #pragma unroll
            for (int i = 0; i < 4; ++i) atomicAdd(oprev + 4 * q + i, Dh[6][i]);
        }

        // gates: tiles {0,1}=r, {2,3}=z, {4,5}=n for units c0 / c0+16
        #pragma unroll
        for (int i = 0; i < 4; ++i) {
            float r0 = fsigmoid(Dh[0][i] + Dx[0][i]);
            float z0 = fsigmoid(Dh[2][i] + Dx[2][i]);
            float n0 = ftanh_fast(fmaf(r0, Dh[4][i], Dx[4][i]));
            h0[i] = fmaf(z0, h0[i] - n0, n0);
            float r1 = fsigmoid(Dh[1][i] + Dx[1][i]);
            float z1 = fsigmoid(Dh[3][i] + Dx[3][i]);
            float n1 = ftanh_fast(fmaf(r1, Dh[5][i], Dx[5][i]));
            h1[i] = fmaf(z1, h1[i] - n1, n1);
            sh[wv][4 * q + i][c0]      = (__bf16)h0[i];
            sh[wv][4 * q + i][c0 + 16] = (__bf16)h1[i];
        }

        xa = nxa; xb = nxb; xc = nxc;
        ocur += ostep;
    }

    // epilogue: out row for time index 199 uses final h (now in LDS)
    {
        bf16x8 Ah = *(const bf16x8*)&sh[wv][c0][q * 8];
        f32x4 cz; cz[0] = 0.f; cz[1] = 0.f; cz[2] = 0.f; cz[3] = 0.f;
        f32x4 P = __builtin_amdgcn_mfma_f32_16x16x32_bf16(Ah, Bh[6], cz, 0, 0, 0);
        if (c0 == 0) {
            float* oprev = ocur - ostep;
            #pragma unroll
            for (int i = 0; i < 4; ++i) atomicAdd(oprev + 4 * q + i, P[i]);
        }
    }
}

extern "C" void kernel_launch(void* const* d_in, const int* in_sizes, int n_in,
                              void* d_out, int out_size, void* d_ws, size_t ws_size,
                              hipStream_t stream) {
    const float* x      = (const float*)d_in[0];
    const float* w_ih_f = (const float*)d_in[1];
    const float* w_hh_f = (const float*)d_in[2];
    const float* b_ih_f = (const float*)d_in[3];
    const float* b_hh_f = (const float*)d_in[4];
    const float* w_ih_b = (const float*)d_in[5];
    const float* w_hh_b = (const float*)d_in[6];
    const float* b_ih_b = (const float*)d_in[7];
    const float* b_hh_b = (const float*)d_in[8];
    const float* fc_w   = (const float*)d_in[9];
    const float* fc_b   = (const float*)d_in[10];
    float* out = (float*)d_out;

    gru_init_out<<<(TT * BB / 4 + 255) / 256, 256, 0, stream>>>(out, fc_b);

    // 512 waves (256 tiles x 2 dirs), 2 waves/block -> 256 blocks = 1/CU
    gru_mfma_kernel<<<256, 128, 0, stream>>>(
        x, w_ih_f, w_hh_f, b_ih_f, b_hh_f,
        w_ih_b, w_hh_b, b_ih_b, b_hh_b, fc_w, out);
}

// Round 5
// 195.714 us; speedup vs baseline: 1.8628x; 1.5150x over previous
//
#include <hip/hip_runtime.h>

#define TT 200
#define BB 4096

typedef __bf16 bf16x8 __attribute__((ext_vector_type(8)));
typedef __bf16 bf16x4 __attribute__((ext_vector_type(4)));
typedef float  f32x4  __attribute__((ext_vector_type(4)));

#define L2E 1.4426950408889634f

__device__ __forceinline__ float fexp2(float x) { return __builtin_amdgcn_exp2f(x); }
__device__ __forceinline__ float frcp(float x)  { return __builtin_amdgcn_rcpf(x); }

// Fallback-path init: fill out[T*B] with fc_b[0].
__global__ void gru_init_out(float* __restrict__ out, const float* __restrict__ fc_b) {
    int i = blockIdx.x * blockDim.x + threadIdx.x;
    float v = fc_b[0];
    ((float4*)out)[i] = make_float4(v, v, v, v);
}

// combine: out = out(fwd partial) + ws(bwd partial) + fc_b
__global__ void gru_combine(float* __restrict__ out, const float* __restrict__ ws,
                            const float* __restrict__ fc_b) {
    int i = blockIdx.x * blockDim.x + threadIdx.x;
    float b = fc_b[0];
    float4 a = ((const float4*)out)[i];
    float4 w = ((const float4*)ws)[i];
    ((float4*)out)[i] = make_float4(a.x + w.x + b, a.y + w.y + b,
                                    a.z + w.z + b, a.w + w.w + b);
}

// MFMA GRU scan, unit-split across 2 waves (all 1024 SIMDs busy).
// Operands swapped vs r4: A = weight tile [16 gate-rows x K=32 units],
// B = h-data [K=32 units x 16 batch] (per-lane frag identical to r4's verified
// layout), D = [gate-row x batch]. Wave wv owns units 16wv..16wv+15: 3 h-MFMAs +
// 3 x-MFMAs (+ fc on wv==1) + gate math for 4 units/lane (24 trans/step, half
// of r4). h ping-pongs through LDS as bf16; one __syncthreads per step couples
// the halves. Gate weights pre-scaled by -log2e (r,z) / 2log2e (n) so
// sigmoid/tanh are rcp(1+exp2(.)) straight off the MFMA result. No atomics:
// fc partial is a coalesced 64B store (q==0 lanes); dirs write separate buffers.
__global__ __launch_bounds__(128, 1) void gru_scan(
    const float* __restrict__ x,
    const float* __restrict__ w_ih_f, const float* __restrict__ w_hh_f,
    const float* __restrict__ b_ih_f, const float* __restrict__ b_hh_f,
    const float* __restrict__ w_ih_b, const float* __restrict__ w_hh_b,
    const float* __restrict__ b_ih_b, const float* __restrict__ b_hh_b,
    const float* __restrict__ fc_w,
    float* __restrict__ out_f, float* __restrict__ out_b,
    int atomic_mode)
{
    const int tile = blockIdx.x;          // batch tile 0..255
    const int dir  = blockIdx.y;          // 0 fwd, 1 bwd
    const int wv   = threadIdx.x >> 6;    // unit-half 0/1
    const int lane = threadIdx.x & 63;
    const int c0   = lane & 15;           // D col = batch row; A row = gate-row
    const int q    = lane >> 4;           // frag k-chunk q*8..; D rows 4q..4q+3
    const int b0   = tile * 16;

    const float* __restrict__ Wih = dir ? w_ih_b : w_ih_f;
    const float* __restrict__ Whh = dir ? w_hh_b : w_hh_f;
    const float* __restrict__ Bih = dir ? b_ih_b : b_ih_f;
    const float* __restrict__ Bhh = dir ? b_hh_b : b_hh_f;
    float* __restrict__ outp = dir ? out_b : out_f;

    // ---- static A fragments (scaled weights) + C bias fragments ----
    // gate g tile rows = 32g + 16wv + [0,16); A[m=c0][k=q*8+j]; C[m=4q+i][n=c0].
    const float gs0 = -L2E, gs1 = -L2E, gs2 = 2.0f * L2E;
    bf16x8 AW[3], AX[3], AFC;
    f32x4  CH[3], CX2, CZ;
    CZ[0] = 0.f; CZ[1] = 0.f; CZ[2] = 0.f; CZ[3] = 0.f;
    #pragma unroll
    for (int g = 0; g < 3; ++g) {
        const float gsc = (g == 0) ? gs0 : (g == 1) ? gs1 : gs2;
        const int arow = 32 * g + 16 * wv + c0;       // weight row for A (m=c0)
        const float* wrow = Whh + arow * 32 + q * 8;
        #pragma unroll
        for (int j = 0; j < 8; ++j) AW[g][j] = (__bf16)(gsc * wrow[j]);
        #pragma unroll
        for (int j = 0; j < 8; ++j)
            AX[g][j] = (q == 0 && j < 3) ? (__bf16)(gsc * Wih[arow * 3 + j]) : (__bf16)0.0f;
        #pragma unroll
        for (int i = 0; i < 4; ++i) {
            const int crow = 32 * g + 16 * wv + 4 * q + i; // bias row for C (m=4q+i)
            CH[g][i] = (g < 2) ? gsc * (Bih[crow] + Bhh[crow])  // full bias into h-MFMA
                               : gsc * Bhh[crow];               // n: bhn only
        }
    }
    #pragma unroll
    for (int i = 0; i < 4; ++i) {
        const int crow = 64 + 16 * wv + 4 * q + i;
        CX2[i] = gs2 * Bih[crow];                               // n: bin via x-MFMA C
    }
    // fc tile: A row 0 = fc_w (K spans all 32 units; both waves hold full h in B)
    #pragma unroll
    for (int j = 0; j < 8; ++j)
        AFC[j] = (c0 == 0) ? (__bf16)fc_w[dir * 32 + q * 8 + j] : (__bf16)0.0f;

    // ---- h state: fp32 in regs (lane owns units 16wv+4q..+3, batch c0),
    //      bf16 ping-pong tile in LDS [16 batch][40 units padded] ----
    float h[4] = {0.f, 0.f, 0.f, 0.f};
    __shared__ __bf16 sh[2][16][40];
    {
        bf16x4 zz; zz[0] = (__bf16)0.f; zz[1] = (__bf16)0.f; zz[2] = (__bf16)0.f; zz[3] = (__bf16)0.f;
        *(bf16x4*)&sh[0][c0][16 * wv + 4 * q] = zz;
    }

    // x pointer-walk: lane loads x[t][b0+c0][0..2] (q-duplicated -> broadcast)
    const int  t_first = dir ? (TT - 1) : 0;
    const long xstep   = dir ? -(long)(BB * 3) : (long)(BB * 3);
    const long ostep   = dir ? -(long)BB : (long)BB;
    const float* xp = x + (size_t)t_first * (BB * 3) + (size_t)(b0 + c0) * 3;
    float* ocur = outp + (size_t)t_first * BB + b0;

    float xa = xp[0], xb = xp[1], xc = xp[2];
    __syncthreads();

    for (int t = 0; t < TT; ++t) {
        // B fragment: full h_{t-1}, one ds_read_b128 per lane
        bf16x8 Bh = *(const bf16x8*)&sh[t & 1][c0][q * 8];

        // prefetch next x early (so the later fc store is newest in vmcnt FIFO)
        const float* xpn = (t < TT - 1) ? (xp + xstep) : xp;
        float nxa = xpn[0], nxb = xpn[1], nxc = xpn[2];
        xp = xpn;

        // B fragment for x (data, unscaled): k<3 rows only (AX zero elsewhere)
        bf16x8 Bx;
        Bx[0] = (__bf16)xa; Bx[1] = (__bf16)xb; Bx[2] = (__bf16)xc;
        Bx[3] = (__bf16)0.f; Bx[4] = (__bf16)0.f; Bx[5] = (__bf16)0.f;
        Bx[6] = (__bf16)0.f; Bx[7] = (__bf16)0.f;

        // x-MFMAs (independent of the ds_read) then h-MFMAs
        f32x4 Dx0 = __builtin_amdgcn_mfma_f32_16x16x32_bf16(AX[0], Bx, CZ,    0, 0, 0);
        f32x4 Dx1 = __builtin_amdgcn_mfma_f32_16x16x32_bf16(AX[1], Bx, CZ,    0, 0, 0);
        f32x4 Dx2 = __builtin_amdgcn_mfma_f32_16x16x32_bf16(AX[2], Bx, CX2,   0, 0, 0);
        f32x4 Dh0 = __builtin_amdgcn_mfma_f32_16x16x32_bf16(AW[0], Bh, CH[0], 0, 0, 0);
        f32x4 Dh1 = __builtin_amdgcn_mfma_f32_16x16x32_bf16(AW[1], Bh, CH[1], 0, 0, 0);
        f32x4 Dh2 = __builtin_amdgcn_mfma_f32_16x16x32_bf16(AW[2], Bh, CH[2], 0, 0, 0);

        // fused FC on h_{t-1} (wave 1 only): D row 0 -> q==0 lanes, 64B coalesced
        if (wv == 1) {
            f32x4 Dfc = __builtin_amdgcn_mfma_f32_16x16x32_bf16(AFC, Bh, CZ, 0, 0, 0);
            if (t > 0 && q == 0) {
                float* oprev = ocur - ostep + c0;
                if (atomic_mode) atomicAdd(oprev, Dfc[0]);
                else             *oprev = Dfc[0];
            }
        }

        // gates for 4 owned units: sigmoid = rcp(1+exp2(s)), tanh = 1-2*rcp(1+exp2(y'))
        #pragma unroll
        for (int i = 0; i < 4; ++i) {
            float r = frcp(1.0f + fexp2(Dh0[i] + Dx0[i]));
            float z = frcp(1.0f + fexp2(Dh1[i] + Dx1[i]));
            float e = fexp2(fmaf(r, Dh2[i], Dx2[i]));
            float n = fmaf(-2.0f, frcp(1.0f + e), 1.0f);
            h[i] = fmaf(z, h[i] - n, n);        // (1-z)*n + z*h
        }
        {
            bf16x4 hv;
            hv[0] = (__bf16)h[0]; hv[1] = (__bf16)h[1];
            hv[2] = (__bf16)h[2]; hv[3] = (__bf16)h[3];
            *(bf16x4*)&sh[(t + 1) & 1][c0][16 * wv + 4 * q] = hv;  // ds_write_b64
        }

        xa = nxa; xb = nxb; xc = nxc;
        ocur += ostep;
        __syncthreads();
    }

    // epilogue: out row for time index T-1 from final h (in sh[0]; TT even)
    if (wv == 1) {
        bf16x8 Bh = *(const bf16x8*)&sh[0][c0][q * 8];
        f32x4 Dfc = __builtin_amdgcn_mfma_f32_16x16x32_bf16(AFC, Bh, CZ, 0, 0, 0);
        if (q == 0) {
            float* oprev = ocur - ostep + c0;
            if (atomic_mode) atomicAdd(oprev, Dfc[0]);
            else             *oprev = Dfc[0];
        }
    }
}

extern "C" void kernel_launch(void* const* d_in, const int* in_sizes, int n_in,
                              void* d_out, int out_size, void* d_ws, size_t ws_size,
                              hipStream_t stream) {
    const float* x      = (const float*)d_in[0];
    const float* w_ih_f = (const float*)d_in[1];
    const float* w_hh_f = (const float*)d_in[2];
    const float* b_ih_f = (const float*)d_in[3];
    const float* b_hh_f = (const float*)d_in[4];
    const float* w_ih_b = (const float*)d_in[5];
    const float* w_hh_b = (const float*)d_in[6];
    const float* b_ih_b = (const float*)d_in[7];
    const float* b_hh_b = (const float*)d_in[8];
    const float* fc_w   = (const float*)d_in[9];
    const float* fc_b   = (const float*)d_in[10];
    float* out = (float*)d_out;
    float* ws  = (float*)d_ws;

    const size_t need = (size_t)TT * BB * sizeof(float);
    dim3 grid(BB / 16, 2);

    if (ws_size >= need) {
        // store path: fwd -> out, bwd -> ws, then combine (adds fc_b)
        gru_scan<<<grid, 128, 0, stream>>>(
            x, w_ih_f, w_hh_f, b_ih_f, b_hh_f,
            w_ih_b, w_hh_b, b_ih_b, b_hh_b, fc_w, out, ws, 0);
        gru_combine<<<(TT * BB / 4) / 256, 256, 0, stream>>>(out, ws, fc_b);
    } else {
        // atomic fallback: init out with fc_b, both dirs accumulate
        gru_init_out<<<(TT * BB / 4 + 255) / 256, 256, 0, stream>>>(out, fc_b);
        gru_scan<<<grid, 128, 0, stream>>>(
            x, w_ih_f, w_hh_f, b_ih_f, b_hh_f,
            w_ih_b, w_hh_b, b_ih_b, b_hh_b, fc_w, out, out, 1);
    }
}

// Round 6
// 190.659 us; speedup vs baseline: 1.9122x; 1.0265x over previous
//
#include <hip/hip_runtime.h>

#define TT 200
#define BB 4096

typedef __bf16 bf16x8 __attribute__((ext_vector_type(8)));
typedef __bf16 bf16x4 __attribute__((ext_vector_type(4)));
typedef float  f32x4  __attribute__((ext_vector_type(4)));

#define L2E 1.4426950408889634f

__device__ __forceinline__ float fexp2(float x) { return __builtin_amdgcn_exp2f(x); }
__device__ __forceinline__ float frcp(float x)  { return __builtin_amdgcn_rcpf(x); }

// LDS-only barrier: __syncthreads() emits "s_waitcnt vmcnt(0) expcnt(0) lgkmcnt(0)"
// which drains our in-flight global store + x-prefetch load EVERY step (~500 cyc,
// the r5 stall). The cross-wave handshake here only needs DS ordering -> wait
// lgkmcnt(0) only; global ops stay in flight across steps.
#define LDS_BARRIER() asm volatile("s_waitcnt lgkmcnt(0)\n\ts_barrier" ::: "memory")

// Fallback-path init: fill out[T*B] with fc_b[0].
__global__ void gru_init_out(float* __restrict__ out, const float* __restrict__ fc_b) {
    int i = blockIdx.x * blockDim.x + threadIdx.x;
    float v = fc_b[0];
    ((float4*)out)[i] = make_float4(v, v, v, v);
}

// combine: out = out(fwd partial) + ws(bwd partial) + fc_b
__global__ void gru_combine(float* __restrict__ out, const float* __restrict__ ws,
                            const float* __restrict__ fc_b) {
    int i = blockIdx.x * blockDim.x + threadIdx.x;
    float b = fc_b[0];
    float4 a = ((const float4*)out)[i];
    float4 w = ((const float4*)ws)[i];
    ((float4*)out)[i] = make_float4(a.x + w.x + b, a.y + w.y + b,
                                    a.z + w.z + b, a.w + w.w + b);
}

// MFMA GRU scan, unit-split across 2 waves (all 1024 SIMDs busy).
// A = weight tile [16 gate-rows x K=32 units], B = h-data [32 units x 16 batch],
// D = [gate-row x batch]. Wave wv owns units 16wv..16wv+15: 3 h-MFMAs + 3 x-MFMAs
// (+ fc on wv==1) + gate math for 4 (unit,batch) elements/lane (24 trans-class ops).
// h ping-pongs through LDS as bf16; LDS_BARRIER per step couples the halves.
// Gate weights pre-scaled by -log2e (r,z) / 2log2e (n) so sigmoid/tanh come
// straight off MFMA as rcp(1+exp2(.)). fc partial: coalesced 64B plain store;
// dirs write separate buffers, combined by gru_combine.
__global__ __launch_bounds__(128, 1) void gru_scan(
    const float* __restrict__ x,
    const float* __restrict__ w_ih_f, const float* __restrict__ w_hh_f,
    const float* __restrict__ b_ih_f, const float* __restrict__ b_hh_f,
    const float* __restrict__ w_ih_b, const float* __restrict__ w_hh_b,
    const float* __restrict__ b_ih_b, const float* __restrict__ b_hh_b,
    const float* __restrict__ fc_w,
    float* __restrict__ out_f, float* __restrict__ out_b,
    int atomic_mode)
{
    const int tile = blockIdx.x;          // batch tile 0..255
    const int dir  = blockIdx.y;          // 0 fwd, 1 bwd
    const int wv   = threadIdx.x >> 6;    // unit-half 0/1
    const int lane = threadIdx.x & 63;
    const int c0   = lane & 15;           // D col = batch row; A row = gate-row
    const int q    = lane >> 4;           // frag k-chunk q*8..; D rows 4q..4q+3
    const int b0   = tile * 16;

    const float* __restrict__ Wih = dir ? w_ih_b : w_ih_f;
    const float* __restrict__ Whh = dir ? w_hh_b : w_hh_f;
    const float* __restrict__ Bih = dir ? b_ih_b : b_ih_f;
    const float* __restrict__ Bhh = dir ? b_hh_b : b_hh_f;
    float* __restrict__ outp = dir ? out_b : out_f;

    // ---- static A fragments (scaled weights) + C bias fragments ----
    const float gs0 = -L2E, gs1 = -L2E, gs2 = 2.0f * L2E;
    bf16x8 AW[3], AX[3], AFC;
    f32x4  CH[3], CX2, CZ;
    CZ[0] = 0.f; CZ[1] = 0.f; CZ[2] = 0.f; CZ[3] = 0.f;
    #pragma unroll
    for (int g = 0; g < 3; ++g) {
        const float gsc = (g == 0) ? gs0 : (g == 1) ? gs1 : gs2;
        const int arow = 32 * g + 16 * wv + c0;       // weight row for A (m=c0)
        const float* wrow = Whh + arow * 32 + q * 8;
        #pragma unroll
        for (int j = 0; j < 8; ++j) AW[g][j] = (__bf16)(gsc * wrow[j]);
        #pragma unroll
        for (int j = 0; j < 8; ++j)
            AX[g][j] = (q == 0 && j < 3) ? (__bf16)(gsc * Wih[arow * 3 + j]) : (__bf16)0.0f;
        #pragma unroll
        for (int i = 0; i < 4; ++i) {
            const int crow = 32 * g + 16 * wv + 4 * q + i; // bias row for C (m=4q+i)
            CH[g][i] = (g < 2) ? gsc * (Bih[crow] + Bhh[crow])
                               : gsc * Bhh[crow];
        }
    }
    #pragma unroll
    for (int i = 0; i < 4; ++i) {
        const int crow = 64 + 16 * wv + 4 * q + i;
        CX2[i] = gs2 * Bih[crow];                      // n-gate x-bias via C
    }
    // fc tile: A row 0 = fc_w over all 32 units (B holds full h)
    #pragma unroll
    for (int j = 0; j < 8; ++j)
        AFC[j] = (c0 == 0) ? (__bf16)fc_w[dir * 32 + q * 8 + j] : (__bf16)0.0f;

    // ---- h state: fp32 in regs; bf16 ping-pong tile in LDS [16][40] ----
    float h[4] = {0.f, 0.f, 0.f, 0.f};
    __shared__ __bf16 sh[2][16][40];
    {
        bf16x4 zz; zz[0] = (__bf16)0.f; zz[1] = (__bf16)0.f; zz[2] = (__bf16)0.f; zz[3] = (__bf16)0.f;
        *(bf16x4*)&sh[0][c0][16 * wv + 4 * q] = zz;
    }

    // x pointer-walk: lane loads x[t][b0+c0][0..2] (q-duplicated -> broadcast)
    const int  t_first = dir ? (TT - 1) : 0;
    const long xstep   = dir ? -(long)(BB * 3) : (long)(BB * 3);
    const long ostep   = dir ? -(long)BB : (long)BB;
    const float* xp = x + (size_t)t_first * (BB * 3) + (size_t)(b0 + c0) * 3;
    float* ocur = outp + (size_t)t_first * BB + b0;

    float xa = xp[0], xb = xp[1], xc = xp[2];
    LDS_BARRIER();

    for (int t = 0; t < TT; ++t) {
        // B fragment: full h_{t-1}, one ds_read_b128 per lane
        bf16x8 Bh = *(const bf16x8*)&sh[t & 1][c0][q * 8];

        // prefetch next x (stays in flight across the LDS-only barrier)
        const float* xpn = (t < TT - 1) ? (xp + xstep) : xp;
        float nxa = xpn[0], nxb = xpn[1], nxc = xpn[2];
        xp = xpn;

        // B fragment for x (data, unscaled): k<3 rows only (AX zero elsewhere)
        bf16x8 Bx;
        Bx[0] = (__bf16)xa; Bx[1] = (__bf16)xb; Bx[2] = (__bf16)xc;
        Bx[3] = (__bf16)0.f; Bx[4] = (__bf16)0.f; Bx[5] = (__bf16)0.f;
        Bx[6] = (__bf16)0.f; Bx[7] = (__bf16)0.f;

        // x-MFMAs (independent of the ds_read) then h-MFMAs
        f32x4 Dx0 = __builtin_amdgcn_mfma_f32_16x16x32_bf16(AX[0], Bx, CZ,    0, 0, 0);
        f32x4 Dx1 = __builtin_amdgcn_mfma_f32_16x16x32_bf16(AX[1], Bx, CZ,    0, 0, 0);
        f32x4 Dx2 = __builtin_amdgcn_mfma_f32_16x16x32_bf16(AX[2], Bx, CX2,   0, 0, 0);
        f32x4 Dh0 = __builtin_amdgcn_mfma_f32_16x16x32_bf16(AW[0], Bh, CH[0], 0, 0, 0);
        f32x4 Dh1 = __builtin_amdgcn_mfma_f32_16x16x32_bf16(AW[1], Bh, CH[1], 0, 0, 0);
        f32x4 Dh2 = __builtin_amdgcn_mfma_f32_16x16x32_bf16(AW[2], Bh, CH[2], 0, 0, 0);

        // fused FC on h_{t-1} (wave 1): D row 0 -> q==0 lanes, 64B coalesced store
        if (wv == 1) {
            f32x4 Dfc = __builtin_amdgcn_mfma_f32_16x16x32_bf16(AFC, Bh, CZ, 0, 0, 0);
            if (t > 0 && q == 0) {
                float* oprev = ocur - ostep + c0;
                if (atomic_mode) atomicAdd(oprev, Dfc[0]);
                else             *oprev = Dfc[0];
            }
        }

        // gates: sigmoid = rcp(1+exp2(s)), tanh = 1-2*rcp(1+exp2(y'))
        #pragma unroll
        for (int i = 0; i < 4; ++i) {
            float r = frcp(1.0f + fexp2(Dh0[i] + Dx0[i]));
            float z = frcp(1.0f + fexp2(Dh1[i] + Dx1[i]));
            float e = fexp2(fmaf(r, Dh2[i], Dx2[i]));
            float n = fmaf(-2.0f, frcp(1.0f + e), 1.0f);
            h[i] = fmaf(z, h[i] - n, n);        // (1-z)*n + z*h
        }
        {
            bf16x4 hv;
            hv[0] = (__bf16)h[0]; hv[1] = (__bf16)h[1];
            hv[2] = (__bf16)h[2]; hv[3] = (__bf16)h[3];
            *(bf16x4*)&sh[(t + 1) & 1][c0][16 * wv + 4 * q] = hv;  // ds_write_b64
        }

        xa = nxa; xb = nxb; xc = nxc;
        ocur += ostep;
        LDS_BARRIER();
    }

    // epilogue: out row for time index T-1 from final h (in sh[0]; TT even)
    if (wv == 1) {
        bf16x8 Bh = *(const bf16x8*)&sh[0][c0][q * 8];
        f32x4 Dfc = __builtin_amdgcn_mfma_f32_16x16x32_bf16(AFC, Bh, CZ, 0, 0, 0);
        if (q == 0) {
            float* oprev = ocur - ostep + c0;
            if (atomic_mode) atomicAdd(oprev, Dfc[0]);
            else             *oprev = Dfc[0];
        }
    }
}

extern "C" void kernel_launch(void* const* d_in, const int* in_sizes, int n_in,
                              void* d_out, int out_size, void* d_ws, size_t ws_size,
                              hipStream_t stream) {
    const float* x      = (const float*)d_in[0];
    const float* w_ih_f = (const float*)d_in[1];
    const float* w_hh_f = (const float*)d_in[2];
    const float* b_ih_f = (const float*)d_in[3];
    const float* b_hh_f = (const float*)d_in[4];
    const float* w_ih_b = (const float*)d_in[5];
    const float* w_hh_b = (const float*)d_in[6];
    const float* b_ih_b = (const float*)d_in[7];
    const float* b_hh_b = (const float*)d_in[8];
    const float* fc_w   = (const float*)d_in[9];
    const float* fc_b   = (const float*)d_in[10];
    float* out = (float*)d_out;
    float* ws  = (float*)d_ws;

    const size_t need = (size_t)TT * BB * sizeof(float);
    dim3 grid(BB / 16, 2);

    if (ws_size >= need) {
        // store path: fwd -> out, bwd -> ws, then combine (adds fc_b)
        gru_scan<<<grid, 128, 0, stream>>>(
            x, w_ih_f, w_hh_f, b_ih_f, b_hh_f,
            w_ih_b, w_hh_b, b_ih_b, b_hh_b, fc_w, out, ws, 0);
        gru_combine<<<(TT * BB / 4) / 256, 256, 0, stream>>>(out, ws, fc_b);
    } else {
        // atomic fallback: init out with fc_b, both dirs accumulate
        gru_init_out<<<(TT * BB / 4 + 255) / 256, 256, 0, stream>>>(out, fc_b);
        gru_scan<<<grid, 128, 0, stream>>>(
            x, w_ih_f, w_hh_f, b_ih_f, b_hh_f,
            w_ih_b, w_hh_b, b_ih_b, b_hh_b, fc_w, out, out, 1);
    }
}